// Round 6
// baseline (46.068 us; speedup 1.0000x reference)
//
#include <hip/hip_runtime.h>
#include <math.h>

#define B_SZ 16
#define K_PTS 4096
#define ALPHA 1.1f

#define JS 16                 // j-tiles per row
#define JTT (K_PTS / JS)      // 256 points per j-tile
#define THR 512               // 8 waves/block
#define NCH 8                 // chains (i-points) per thread

#define BIGF 3.0e38f

__device__ __forceinline__ void insert2(float d, float& m0, float& m1) {
    m1 = __builtin_amdgcn_fmed3f(d, m0, m1);
    m0 = fminf(d, m0);
}
__device__ __forceinline__ void insert3(float d, float& m0, float& m1, float& m2) {
    m2 = __builtin_amdgcn_fmed3f(d, m1, m2);
    m1 = __builtin_amdgcn_fmed3f(d, m0, m1);
    m0 = fminf(d, m0);
}

// Phase 1: grid (JS, B) = 256 blocks, one per CU; 512 thr x 8 chains = all
// 4096 i-points per block vs one 256-point j-tile. Every block is identical:
// chain 0 runs top-3 (insert3); the thread whose chain-cstar point lies in
// this j-tile has that point swapped into chain 0 and drops m0 (= self, the
// strict tile min since d'_self = -||xi||^2 < d' of any other j). Other
// chains run top-2. d' = -2<xi,xj> + ||xj||^2 (shifted; order-preserving).
__global__ __launch_bounds__(THR) void sor_partial2(
    const float* __restrict__ x, float* __restrict__ ws)
{
    __shared__ float4 pts[JTT];   // 4 KiB: (x, y, z, ||x||^2)
    const int b  = blockIdx.y;
    const int js = blockIdx.x;
    const int j0 = js * JTT;
    const float* xb = x + (size_t)b * K_PTS * 3;

    for (int p = threadIdx.x; p < JTT; p += THR) {
        float a0 = xb[(j0 + p) * 3 + 0];
        float a1 = xb[(j0 + p) * 3 + 1];
        float a2 = xb[(j0 + p) * 3 + 2];
        pts[p] = make_float4(a0, a1, a2, a0 * a0 + a1 * a1 + a2 * a2);
    }
    __syncthreads();

    const int tid = threadIdx.x;
    const int cstar = js >> 1;                       // chain whose i-range meets this j-tile
    const bool has_self = ((tid >> 8) == (js & 1));  // thread's chain-cstar point is in tile

    // chain c -> point index; swap chain 0 <-> cstar for has_self threads.
    // idx[] is only ever indexed with compile-time constants (no scratch).
    int idx[NCH];
    #pragma unroll
    for (int c = 0; c < NCH; ++c) {
        int p = tid + c * THR;
        if (c == 0) p = has_self ? (tid + cstar * THR) : tid;
        else        p = (has_self && (c == cstar)) ? tid : p;
        idx[c] = p;
    }

    float x2[NCH], y2[NCH], z2[NCH], m0[NCH], m1[NCH];
    #pragma unroll
    for (int c = 0; c < NCH; ++c) {
        const float* p = xb + (size_t)idx[c] * 3;
        x2[c] = -2.0f * p[0];
        y2[c] = -2.0f * p[1];
        z2[c] = -2.0f * p[2];
        m0[c] = BIGF; m1[c] = BIGF;
    }
    float m2_0 = BIGF;   // third slot for chain 0 only

    #pragma unroll 4
    for (int j = 0; j < JTT; ++j) {
        const float4 pj = pts[j];
        {   // chain 0: top-3
            float t = fmaf(z2[0], pj.z, pj.w);
            t = fmaf(y2[0], pj.y, t);
            float d = fmaf(x2[0], pj.x, t);
            insert3(d, m0[0], m1[0], m2_0);
        }
        #pragma unroll
        for (int c = 1; c < NCH; ++c) {
            float t = fmaf(z2[c], pj.z, pj.w);
            t = fmaf(y2[c], pj.y, t);
            float d = fmaf(x2[c], pj.x, t);
            insert2(d, m0[c], m1[c]);
        }
    }

    float* wbase = ws + (size_t)((b * JS + js) * 2) * K_PTS;
    // chain 0: drop m0 (self) iff has_self
    {
        const float s0 = has_self ? m1[0] : m0[0];
        const float s1 = has_self ? m2_0  : m1[0];
        wbase[idx[0]]         = s0;
        wbase[K_PTS + idx[0]] = s1;
    }
    #pragma unroll
    for (int c = 1; c < NCH; ++c) {
        wbase[idx[c]]         = m0[c];
        wbase[K_PTS + idx[c]] = m1[c];
    }
}

// Merge 16 tiles x 2 candidates per point -> mean 2NN distance. 256 blocks.
__global__ __launch_bounds__(256) void sor_merge(
    const float* __restrict__ x, const float* __restrict__ ws,
    float* __restrict__ value)
{
    const int gid = blockIdx.x * 256 + threadIdx.x;   // 0 .. B*K-1
    const int b = gid >> 12;
    const int i = gid & (K_PTS - 1);

    float m0 = BIGF, m1 = BIGF;
    #pragma unroll
    for (int js = 0; js < JS; ++js) {
        const float* w = ws + (size_t)((b * JS + js) * 2) * K_PTS + i;
        insert2(w[0], m0, m1);
        insert2(w[K_PTS], m0, m1);
    }
    const float a0 = x[(size_t)gid * 3 + 0];
    const float a1 = x[(size_t)gid * 3 + 1];
    const float a2 = x[(size_t)gid * 3 + 2];
    const float xx = a0 * a0 + a1 * a1 + a2 * a2;
    // un-shift: true distances are m' + ||xi||^2; (m0,m1) = 2NN sorted.
    value[gid] = ((m0 + xx) + (m1 + xx)) * 0.5f;
}

// One block per batch: mean/std(ddof=1) -> threshold -> mask + zeroed points.
__global__ __launch_bounds__(1024) void sor_mask_kernel(
    const float* __restrict__ x, float* __restrict__ out)
{
    const int b = blockIdx.x;
    const int tid = threadIdx.x;
    float* value = out + (size_t)B_SZ * K_PTS * 3;
    float* selpc = out;

    __shared__ float red[16];
    __shared__ float sh_mean, sh_thr;

    float v[4];
    float s = 0.0f;
    #pragma unroll
    for (int k = 0; k < 4; ++k) {
        v[k] = value[b * K_PTS + tid + k * 1024];
        s += v[k];
    }
    #pragma unroll
    for (int off = 32; off > 0; off >>= 1) s += __shfl_down(s, off, 64);
    if ((tid & 63) == 0) red[tid >> 6] = s;
    __syncthreads();
    if (tid == 0) {
        float t = 0.0f;
        for (int w = 0; w < 16; ++w) t += red[w];
        sh_mean = t * (1.0f / (float)K_PTS);
    }
    __syncthreads();
    const float mean = sh_mean;

    float q = 0.0f;
    #pragma unroll
    for (int k = 0; k < 4; ++k) { float dv = v[k] - mean; q += dv * dv; }
    #pragma unroll
    for (int off = 32; off > 0; off >>= 1) q += __shfl_down(q, off, 64);
    if ((tid & 63) == 0) red[tid >> 6] = q;
    __syncthreads();
    if (tid == 0) {
        float t = 0.0f;
        for (int w = 0; w < 16; ++w) t += red[w];
        sh_thr = mean + ALPHA * sqrtf(t / (float)(K_PTS - 1));
    }
    __syncthreads();
    const float thr = sh_thr;

    #pragma unroll
    for (int k = 0; k < 4; ++k) {
        const int i = tid + k * 1024;
        const bool keep = v[k] <= thr;
        value[b * K_PTS + i] = keep ? 1.0f : 0.0f;
        const size_t base = ((size_t)b * K_PTS + i) * 3;
        float x0 = x[base + 0];
        float x1 = x[base + 1];
        float x2 = x[base + 2];
        selpc[base + 0] = keep ? x0 : 0.0f;
        selpc[base + 1] = keep ? x1 : 0.0f;
        selpc[base + 2] = keep ? x2 : 0.0f;
    }
}

// ---- Fallback (round-1 structure) used only if d_ws is too small ----
__global__ __launch_bounds__(256) void sor_value_kernel(
    const float* __restrict__ x, float* __restrict__ value)
{
    __shared__ float4 pts[K_PTS];
    const int b = blockIdx.y;
    const float* xb = x + (size_t)b * K_PTS * 3;
    for (int p = threadIdx.x; p < K_PTS; p += 256) {
        float a0 = xb[p * 3 + 0];
        float a1 = xb[p * 3 + 1];
        float a2 = xb[p * 3 + 2];
        pts[p] = make_float4(a0, a1, a2, a0 * a0 + a1 * a1 + a2 * a2);
    }
    __syncthreads();
    const int i = blockIdx.x * 256 + threadIdx.x;
    const float4 pi = pts[i];
    float m0 = BIGF, m1 = BIGF, m2 = BIGF;
    #pragma unroll 8
    for (int j = 0; j < K_PTS; ++j) {
        float4 pj = pts[j];
        float dot = pi.x * pj.x + pi.y * pj.y + pi.z * pj.z;
        float d = (pi.w - 2.0f * dot) + pj.w;
        insert3(d, m0, m1, m2);
    }
    value[b * K_PTS + i] = 0.5f * (m1 + m2);
}

extern "C" void kernel_launch(void* const* d_in, const int* in_sizes, int n_in,
                              void* d_out, int out_size, void* d_ws, size_t ws_size,
                              hipStream_t stream)
{
    const float* x = (const float*)d_in[0];
    float* out = (float*)d_out;
    float* value = out + (size_t)B_SZ * K_PTS * 3;

    const size_t ws_needed = (size_t)B_SZ * JS * 2 * K_PTS * sizeof(float); // 8.4 MiB

    if (ws_size >= ws_needed) {
        float* ws = (float*)d_ws;
        dim3 gA(JS, B_SZ);   // (16, 16) = 256 blocks, one per CU
        sor_partial2<<<gA, THR, 0, stream>>>(x, ws);
        sor_merge<<<(B_SZ * K_PTS) / 256, 256, 0, stream>>>(x, ws, value);
    } else {
        dim3 g1(K_PTS / 256, B_SZ);
        sor_value_kernel<<<g1, 256, 0, stream>>>(x, value);
    }
    sor_mask_kernel<<<B_SZ, 1024, 0, stream>>>(x, out);
}